// Round 3
// baseline (2429.705 us; speedup 1.0000x reference)
//
#include <hip/hip_runtime.h>
#include <stdint.h>

typedef __attribute__((ext_vector_type(4))) float f32x4;

#define T_WIN 4
#define BSZ   128
#define SSZ   64
#define DDIM  3136
#define FDIM  512
#define HDIM  512
#define LDIM  18
#define ROWS  8192   // B*S
#define KB    16

// Per-gemm chunk-buffer stride = M*N floats; chunk q lives at C + q*M*N.
struct GArgs { const void* A; const float* B; float* C; int M; };

// OpenBLAS K-chunk bounds for K=3136 (GEMM_Q=384, tail halving) — validated R3/R4.
__device__ __forceinline__ void kchunk3136(int z, int& ks, int& ke) {
  ks = (z <= 7) ? 384 * z : 2912;
  ke = (z <= 6) ? 384 * (z + 1) : ((z == 7) ? 2912 : 3136);
}

// ============================================================================
// fp32 GEMM, all K-chunks in ONE launch (z = chunk): writes chunk partial sum
// (ascending-k single-accumulator fma chain from zero) to its own buffer.
// The in-order chunk adds happen in the consumer kernels (bitwise = RMW chain).
//
// R7 structure: same 128x128 tile / LDS dbuf / 1-barrier pipeline as R6, but
// 256 threads x 8x8 outputs (was 128 x 16x8). Rationale (R6 counters):
// occupancy pinned at 21.5% ~= 2 waves/SIMD by the UNIFIED reg file
// (128 AGPR acc + ~128 VGPR = 256/wave). 8x8 acc = 64 regs -> ~115 total ->
// 4 waves/SIMD. Per-output FMA chain (ascending k, single acc) is UNCHANGED:
// each output still computed by one thread -> bitwise identical results.
//
// smem layout (floats): A0 [0,2048) A1 [2048,4096) B0 [4096,6144) B1 [6144,8192)
// LDS byte offsets for M0: B0=16384, B1=24576.
//
// SMALLS: logical ids >= 1024 handle the prox/trunk 512-row GEMMs (g1/g2).
// AMODE 0: A fp32;  AMODE 1: A uint8 (0/1 spikes -> exact products).
// ============================================================================
template<int AMODE, int SMALLS>
__global__ __launch_bounds__(256, 4) void gemm_chunks(GArgs g0, GArgs g1, GArgs g2,
                                                      int N, int K, int kcmode) {
  // bijective XCD swizzle (nwg % 8 == 0): keeps the 4 y-siblings of each xb
  // (same A K-slice) co-resident on one XCD -> A L2-hit 3x. (validated R5)
  const int chunk = gridDim.x >> 3;
  const int orig  = blockIdx.x;
  const int lin   = (orig & 7) * chunk + (orig >> 3);

  GArgs g = g0;
  int xb, y;
  if (SMALLS && lin >= 1024) {
    const int sidx = lin - 1024;          // 0..31
    g  = (sidx >> 4) ? g2 : g1;
    xb = (sidx >> 2) & 3;
    y  = sidx & 3;
  } else {
    xb = lin >> 2;
    y  = lin & 3;
  }

  int ks, ke;
  if (kcmode == 0) kchunk3136(blockIdx.z, ks, ke);
  else { ks = blockIdx.z * 256; ke = ks + 256; }
  const int NT = (ke - ks) / KB;          // 24 / 14 / 16 — always >= 2

  const int m0 = xb * 128;
  const int n0 = y * 128;
  float* C = g.C + (size_t)blockIdx.z * g.M * N;

  __shared__ float smem[8192];            // 32 KB: A dbuf + B dbuf

  const int tid = threadIdx.x;
  const int tx = tid & 15;            // n: cols tx*4..+3 and 64+tx*4..+3
  const int ty = tid >> 4;            // m: rows ty*8..+7  (16 groups x 8 = 128)
  const int arow = tid >> 1;          // A stage: half-row per thread
  const int ahalf = tid & 1;          // 8 k-floats each
  const int lane = tid & 63;
  const int wv   = tid >> 6;          // wave 0..3

  const float*   Af = (const float*)g.A;
  const uint8_t* A8 = (const uint8_t*)g.A;

  float acc[8][8];
#pragma unroll
  for (int i = 0; i < 8; i++)
#pragma unroll
    for (int j = 0; j < 8; j++) acc[i][j] = 0.f;

  // ---- A prefetch registers (transpose path): 8 k-floats of one row ----
  f32x4 av[2];
  auto load_A = [&](int k0) {
    if (AMODE == 0) {
      const float* ap = Af + (size_t)(m0 + arow) * K + k0 + ahalf * 8;
#pragma unroll
      for (int c = 0; c < 2; c++) av[c] = *(const f32x4*)(ap + 4 * c);
    } else {
      uint2 wrd = *(const uint2*)(A8 + (size_t)(m0 + arow) * K + k0 + ahalf * 8);
      uint32_t u[2] = {wrd.x, wrd.y};
#pragma unroll
      for (int c = 0; c < 2; c++) {
        av[c][0] = (float)(u[c] & 255u);
        av[c][1] = (float)((u[c] >> 8) & 255u);
        av[c][2] = (float)((u[c] >> 16) & 255u);
        av[c][3] = (float)((u[c] >> 24) & 255u);
      }
    }
  };

  // ---- B tile stage: global_load_lds, 1 KB per wave-instr, 8 chunks/tile ----
  // chunk c covers floats [c*256, c*256+256) of the [16][128] tile:
  // lane covers k = c*2 + (lane>>5), n = (lane&31)*4.  4 waves x 2 instrs.
  const int bkk = lane >> 5;
  const int bnn = (lane & 31) * 4;
  auto stage_B = [&](int nb, int k0) {
#pragma unroll
    for (int r = 0; r < 2; r++) {
      const int c = r * 4 + wv;
      const float* gp = g.B + (size_t)(k0 + c * 2 + bkk) * N + n0 + bnn;
      uint32_t m0v = (uint32_t)((4096 + nb * 2048 + c * 256) * 4);
      m0v = __builtin_amdgcn_readfirstlane(m0v);
      asm volatile("s_mov_b32 m0, %0\n\t"
                   "global_load_lds_dwordx4 %1, off\n\t"
                   :: "s"(m0v), "v"(gp) : "memory");
    }
  };

  // ---- A tile write: reg -> LDS transposed [k][m] (8 scalar ds_writes) ----
  auto write_A = [&](int nb) {
    const int abase = nb * 2048;
#pragma unroll
    for (int c = 0; c < 2; c++)
#pragma unroll
      for (int j = 0; j < 4; j++)
        smem[abase + (ahalf * 8 + 4 * c + j) * 128 + arow] = av[c][j];
  };

  // ---- prologue: tile 0 into buf 0, prefetch A(tile 1) ----
  load_A(ks);
  stage_B(0, ks);
  write_A(0);
  load_A(ks + KB);                        // NT >= 2 always
  asm volatile("s_waitcnt vmcnt(0)" ::: "memory");
  __syncthreads();

  for (int it = 0; it < NT; ++it) {
    const int k0 = ks + it * KB;
    const int abase = (it & 1) * 2048;
    const int bbase = 4096 + (it & 1) * 2048;

    if (it + 1 < NT) {
      const int nb = (it + 1) & 1;
      stage_B(nb, k0 + KB);               // async -> other buffer
      write_A(nb);                        // ds_write, overlaps FMAs below
      if (it + 2 < NT) load_A(k0 + 2 * KB);
    }

    // ---- inner k (ascending, single accumulator per output) ----
#pragma unroll 4
    for (int k = 0; k < KB; k++) {
      f32x4 a0 = *(const f32x4*)&smem[abase + k * 128 + ty * 8];
      f32x4 a1 = *(const f32x4*)&smem[abase + k * 128 + ty * 8 + 4];
      f32x4 b0 = *(const f32x4*)&smem[bbase + k * 128 + tx * 4];
      f32x4 b1 = *(const f32x4*)&smem[bbase + k * 128 + 64 + tx * 4];
      float a[8] = {a0[0], a0[1], a0[2], a0[3], a1[0], a1[1], a1[2], a1[3]};
      float b[8] = {b0[0], b0[1], b0[2], b0[3], b1[0], b1[1], b1[2], b1[3]};
#pragma unroll
      for (int i = 0; i < 8; i++)
#pragma unroll
        for (int j = 0; j < 8; j++)
          acc[i][j] = __fmaf_rn(a[i], b[j], acc[i][j]);
    }

    asm volatile("s_waitcnt vmcnt(0)" ::: "memory");   // next tile's B landed
    __syncthreads();                                   // writes visible, reads done
  }

  // ---- store chunk partial sums ----
#pragma unroll
  for (int i = 0; i < 8; i++) {
    float* cp = C + (size_t)(m0 + ty * 8 + i) * N + n0;
    f32x4 v0 = {acc[i][0], acc[i][1], acc[i][2], acc[i][3]};
    f32x4 v1 = {acc[i][4], acc[i][5], acc[i][6], acc[i][7]};
    *(f32x4*)(cp + tx * 4) = v0;
    *(f32x4*)(cp + 64 + tx * 4) = v1;
  }
}

// ============================================================================
// p/t filters: in-order 9-chunk reduction (bitwise = sequential RMW adds),
// then exact np LIF chains. P/Tf are post-update states.
// ============================================================================
__global__ __launch_bounds__(256) void filter_pt9(const float* __restrict__ Cp,
                                                  const float* __restrict__ Ct,
                                                  float* __restrict__ P,
                                                  float* __restrict__ Tf) {
  const size_t CH = (size_t)T_WIN * BSZ * FDIM;   // 262144 floats
  int idx = blockIdx.x * 256 + threadIdx.x;   // 16384: (b, f/4)
  int b = idx >> 7;
  int fc = (idx & 127) << 2;
  f32x4 p = {0.f, 0.f, 0.f, 0.f}, t = {0.f, 0.f, 0.f, 0.f};
  for (int tt = 0; tt < T_WIN; tt++) {
    size_t o = (size_t)(tt * BSZ + b) * FDIM + fc;
    f32x4 x = *(const f32x4*)&Cp[o];
    f32x4 y = *(const f32x4*)&Ct[o];
    for (int q = 1; q < 9; q++) {
      f32x4 xq = *(const f32x4*)&Cp[o + q * CH];
      f32x4 yq = *(const f32x4*)&Ct[o + q * CH];
#pragma unroll
      for (int c = 0; c < 4; c++) { x[c] = __fadd_rn(x[c], xq[c]); y[c] = __fadd_rn(y[c], yq[c]); }
    }
#pragma unroll
    for (int c = 0; c < 4; c++) {
      p[c] = __fadd_rn(p[c], __fmul_rn(__fsub_rn(x[c], p[c]), 0.5f));
      t[c] = __fadd_rn(t[c], __fmul_rn(__fsub_rn(y[c], t[c]), 0.5f));
    }
    *(f32x4*)&P[o] = p;
    *(f32x4*)&Tf[o] = t;
  }
}

// ============================================================================
// soma LIF: in-order 9-chunk reduction of dist, then exact np chain -> spikes.
// ============================================================================
__global__ __launch_bounds__(256) void lif_soma9(const float* __restrict__ Cd,
                                                 const float* __restrict__ P,
                                                 const float* __restrict__ Tf,
                                                 uint8_t* __restrict__ emb) {
  const size_t CH = (size_t)T_WIN * ROWS * FDIM;  // 16,777,216 floats
  int idx = blockIdx.x * 256 + threadIdx.x;   // 1,048,576: (r, f/4)
  int r = idx >> 7;
  int fc = (idx & 127) << 2;
  int b = r >> 6;
  f32x4 d = {0.f, 0.f, 0.f, 0.f}, soma = {0.f, 0.f, 0.f, 0.f};
#pragma unroll
  for (int t = 0; t < T_WIN; t++) {
    size_t o = (size_t)(t * ROWS + r) * FDIM + fc;
    f32x4 x = *(const f32x4*)&Cd[o];
#pragma unroll
    for (int q = 1; q < 9; q++) {
      f32x4 xq = *(const f32x4*)&Cd[o + q * CH];
#pragma unroll
      for (int c = 0; c < 4; c++) x[c] = __fadd_rn(x[c], xq[c]);
    }
    f32x4 pv = *(const f32x4*)&P[(size_t)(t * BSZ + b) * FDIM + fc];
    f32x4 tv = *(const f32x4*)&Tf[(size_t)(t * BSZ + b) * FDIM + fc];
    uint32_t bits = 0;
#pragma unroll
    for (int c = 0; c < 4; c++) {
      d[c] = __fadd_rn(d[c], __fmul_rn(__fsub_rn(x[c], d[c]), 0.5f));
      float pd = __fmul_rn(pv[c], d[c]);          // p*d (must NOT contract)
      float u  = __fadd_rn(pd, tv[c]);            // + t
      float w  = __fsub_rn(u, soma[c]);           // - soma
      soma[c] = __fadd_rn(soma[c], __fmul_rn(w, 0.5f));
      if (soma[c] >= 0.5f) { bits |= (1u << (8 * c)); soma[c] = 0.f; }
    }
    *(uint32_t*)&emb[o] = bits;
  }
}

// ============================================================================
// hidden LIF: in-order 2-chunk reduction of H, +b1 first, exact chain -> counts.
// ============================================================================
__global__ __launch_bounds__(256) void lif_hidden2(const float* __restrict__ Hc,
                                                   const float* __restrict__ b1,
                                                   uint8_t* __restrict__ cnt) {
  const size_t CH = (size_t)T_WIN * ROWS * FDIM;
  int idx = blockIdx.x * 256 + threadIdx.x;   // (r, f/4)
  int r = idx >> 7;
  int fc = (idx & 127) << 2;
  f32x4 bb = *(const f32x4*)&b1[fc];
  f32x4 lif = {0.f, 0.f, 0.f, 0.f};
  uint32_t counts = 0;
#pragma unroll
  for (int t = 0; t < T_WIN; t++) {
    size_t o = (size_t)(t * ROWS + r) * FDIM + fc;
    f32x4 h0 = *(const f32x4*)&Hc[o];
    f32x4 h1 = *(const f32x4*)&Hc[o + CH];
#pragma unroll
    for (int c = 0; c < 4; c++) {
      float hv = __fadd_rn(__fadd_rn(h0[c], h1[c]), bb[c]);
      lif[c] = __fadd_rn(lif[c], __fmul_rn(__fsub_rn(hv, lif[c]), 0.5f));
      if (lif[c] >= 0.5f) { counts += (1u << (8 * c)); lif[c] = 0.f; }
    }
  }
  *(uint32_t*)&cnt[(size_t)r * FDIM + fc] = counts;
}

// ============================================================================
// out[b,l,s] = sum_k (cnt[r,k]/4)*W2[k,l] + b2[l]; k ascending, zero-skip
// bitwise exact (counts/4 are exact). Writes final output directly.
// ============================================================================
__global__ __launch_bounds__(256) void out_kernel(const uint8_t* __restrict__ cnt,
                                                  const float* __restrict__ W2,
                                                  const float* __restrict__ b2,
                                                  float* __restrict__ out) {
  int idx = blockIdx.x * 256 + threadIdx.x;   // 147456 = 8192*18
  int r = idx / LDIM;
  int j = idx - r * LDIM;
  const uint4* crow = (const uint4*)(cnt + (size_t)r * HDIM);
  float acc = 0.f;
  for (int q = 0; q < HDIM / 16; q++) {
    uint4 wrd = crow[q];
    uint32_t u[4] = {wrd.x, wrd.y, wrd.z, wrd.w};
#pragma unroll
    for (int wq = 0; wq < 4; wq++)
#pragma unroll
      for (int s = 0; s < 4; s++) {
        uint32_t c = (u[wq] >> (8 * s)) & 255u;
        if (c) acc = __fmaf_rn((float)c * 0.25f, W2[(16 * q + 4 * wq + s) * LDIM + j], acc);
      }
  }
  int b = r >> 6, s = r & 63;
  out[(size_t)b * (LDIM * SSZ) + j * SSZ + s] = __fadd_rn(acc, b2[j]);
}

// ---------- workspace layout (~616 MB; harness ws is ~1.6 GB per fill size) ----------
// Cd   9 x 64 MB  @ 0            (603,979,776)   dist chunk partial sums
//   (Hc 2 x 64 MB aliases Cd[0..1] — Cd dead once lif_soma9 completes)
// Cp   9 x 1 MB   @ 603,979,776  (  9,437,184)
// Ct   9 x 1 MB   @ 613,416,960  (  9,437,184)
// P    1 MB       @ 622,854,144
// Tf   1 MB       @ 623,902,720
// emb  16 MB      @ 624,951,296
// cnt  4 MB       @ 641,728,512   -> total 645,922,816

extern "C" void kernel_launch(void* const* d_in, const int* in_sizes, int n_in,
                              void* d_out, int out_size, void* d_ws, size_t ws_size,
                              hipStream_t stream) {
  const float* se     = (const float*)d_in[0];
  const float* te     = (const float*)d_in[1];
  const float* ee     = (const float*)d_in[2];
  const float* Wprox  = (const float*)d_in[3];
  const float* Wdist  = (const float*)d_in[4];
  const float* Wtrunk = (const float*)d_in[5];
  const float* W1     = (const float*)d_in[6];
  const float* b1     = (const float*)d_in[7];
  const float* W2     = (const float*)d_in[8];
  const float* b2     = (const float*)d_in[9];

  char* ws = (char*)d_ws;
  float*   Cd   = (float*)(ws);
  float*   Hc   = (float*)(ws);                 // aliases Cd[0..1] (dead by then)
  float*   Cp   = (float*)(ws + 603979776);
  float*   Ct   = (float*)(ws + 613416960);
  float*   P    = (float*)(ws + 622854144);
  float*   Tf   = (float*)(ws + 623902720);
  uint8_t* emb8 = (uint8_t*)(ws + 624951296);
  uint8_t* cnt8 = (uint8_t*)(ws + 641728512);

  // 1. ALL input-GEMM K-chunks in one launch (z = chunk 0..8).
  GArgs gd{te, Wdist, Cd, T_WIN * ROWS};
  GArgs gp{se, Wprox, Cp, T_WIN * BSZ};
  GArgs gt{ee, Wtrunk, Ct, T_WIN * BSZ};
  gemm_chunks<0, 1><<<dim3(1056, 1, 9), 256, 0, stream>>>(gd, gp, gt, FDIM, DDIM, 0);

  // 2. p/t filters (9-chunk in-order reduce + exact chains)
  filter_pt9<<<64, 256, 0, stream>>>(Cp, Ct, P, Tf);

  // 3. soma LIF (9-chunk in-order reduce + exact chains) -> binary spikes
  lif_soma9<<<4096, 256, 0, stream>>>(Cd, P, Tf, emb8);

  // 4. H = emb @ W1, both K-chunks {0..256,256..512} in one launch (over Cd, dead)
  GArgs gh{emb8, W1, Hc, T_WIN * ROWS};
  gemm_chunks<1, 0><<<dim3(1024, 1, 2), 256, 0, stream>>>(gh, gh, gh, HDIM, FDIM, 1);

  // 5. hidden LIF (2-chunk in-order reduce) -> spike counts
  lif_hidden2<<<4096, 256, 0, stream>>>(Hc, b1, cnt8);

  // 6. output GEMM + b2 + [B,LAST,S] transpose, fp32
  out_kernel<<<576, 256, 0, stream>>>(cnt8, W2, b2, (float*)d_out);
}

// Round 4
// 2014.578 us; speedup vs baseline: 1.2061x; 1.2061x over previous
//
#include <hip/hip_runtime.h>
#include <stdint.h>

typedef __attribute__((ext_vector_type(4))) float f32x4;

#define T_WIN 4
#define BSZ   128
#define SSZ   64
#define DDIM  3136
#define FDIM  512
#define HDIM  512
#define LDIM  18
#define ROWS  8192   // B*S
#define KB    8

// Per-gemm chunk-buffer stride = M*N floats; chunk q lives at C + q*M*N.
struct GArgs { const void* A; const float* B; float* C; int M; };

// OpenBLAS K-chunk bounds for K=3136 (GEMM_Q=384, tail halving) — validated R3/R4.
__device__ __forceinline__ void kchunk3136(int z, int& ks, int& ke) {
  ks = (z <= 7) ? 384 * z : 2912;
  ke = (z <= 6) ? 384 * (z + 1) : ((z == 7) ? 2912 : 3136);
}

// ============================================================================
// fp32 GEMM, all K-chunks in ONE launch (z = chunk): writes chunk partial sum
// (ascending-k single-accumulator fma chain from zero) to its own buffer.
// The in-order chunk adds happen in the consumer kernels (bitwise = RMW chain).
//
// R8 = R6 structure (128 thr, 16x8 acc — the proven-clean reg allocation;
// LDS dbuf, global_load_lds B-staging, 1 barrier/tile) with KB 16->8.
// Rationale (R6/R7 counters): R6 occupancy was LDS-capped (32 KB -> ~4
// blocks/CU -> 2 waves/SIMD; barrier drains uncovered). R7 proved the reg
// budget must NOT be squeezed (acc got AGPR'd -> 3x VALU ops, 33 TF).
// KB=8 halves LDS to 16 KB -> 8+ blocks/CU -> ~4 waves/SIMD with the same
// per-thread codegen. K-order within a chunk stays ascending per output ->
// bitwise identical results.
//
// smem layout (floats): A0 [0,1024) A1 [1024,2048) B0 [2048,3072) B1 [3072,4096)
// LDS byte offsets for M0: B0=8192, B1=12288.
//
// SMALLS: logical ids >= 1024 handle the prox/trunk 512-row GEMMs (g1/g2).
// AMODE 0: A fp32;  AMODE 1: A uint8 (0/1 spikes -> exact products).
// ============================================================================
template<int AMODE, int SMALLS>
__global__ __launch_bounds__(128, 2) void gemm_chunks(GArgs g0, GArgs g1, GArgs g2,
                                                      int N, int K, int kcmode) {
  // bijective XCD swizzle (nwg % 8 == 0): keeps the 4 y-siblings of each xb
  // (same A K-slice) co-resident on one XCD -> A L2-hit 3x. (validated R5)
  const int chunk = gridDim.x >> 3;
  const int orig  = blockIdx.x;
  const int lin   = (orig & 7) * chunk + (orig >> 3);

  GArgs g = g0;
  int xb, y;
  if (SMALLS && lin >= 1024) {
    const int sidx = lin - 1024;          // 0..31
    g  = (sidx >> 4) ? g2 : g1;
    xb = (sidx >> 2) & 3;
    y  = sidx & 3;
  } else {
    xb = lin >> 2;
    y  = lin & 3;
  }

  int ks, ke;
  if (kcmode == 0) kchunk3136(blockIdx.z, ks, ke);
  else { ks = blockIdx.z * 256; ke = ks + 256; }
  const int NT = (ke - ks) / KB;          // 48 / 28 / 32 — always >= 2

  const int m0 = xb * 128;
  const int n0 = y * 128;
  float* C = g.C + (size_t)blockIdx.z * g.M * N;

  __shared__ float smem[4096];            // 16 KB: A dbuf + B dbuf

  const int tid = threadIdx.x;
  const int tx = tid & 15;            // n: cols tx*4..+3 and 64+tx*4..+3
  const int ty = tid >> 4;            // m: rows ty*16..+15  (8 groups x 16)
  const int am = tid;                 // A stage: one row per thread, 8 k-floats
  const int lane = tid & 63;
  const int wv   = tid >> 6;          // wave 0..1

  const float*   Af = (const float*)g.A;
  const uint8_t* A8 = (const uint8_t*)g.A;

  float acc[16][8];
#pragma unroll
  for (int i = 0; i < 16; i++)
#pragma unroll
    for (int j = 0; j < 8; j++) acc[i][j] = 0.f;

  // ---- A prefetch registers (transpose path): 8 k-floats of one row ----
  f32x4 av[2];
  auto load_A = [&](int k0) {
    if (AMODE == 0) {
      const float* ap = Af + (size_t)(m0 + am) * K + k0;
#pragma unroll
      for (int c = 0; c < 2; c++) av[c] = *(const f32x4*)(ap + 4 * c);
    } else {
      uint2 wrd = *(const uint2*)(A8 + (size_t)(m0 + am) * K + k0);
      uint32_t u[2] = {wrd.x, wrd.y};
#pragma unroll
      for (int c = 0; c < 2; c++) {
        av[c][0] = (float)(u[c] & 255u);
        av[c][1] = (float)((u[c] >> 8) & 255u);
        av[c][2] = (float)((u[c] >> 16) & 255u);
        av[c][3] = (float)((u[c] >> 24) & 255u);
      }
    }
  };

  // ---- B tile stage: global_load_lds, 1 KB per wave-instr, 4 chunks/tile ----
  // chunk c covers floats [c*256, c*256+256) of the [8][128] tile:
  // lane covers k = c*2 + (lane>>5), n = (lane&31)*4.  2 waves x 2 instrs.
  const int bkk = lane >> 5;
  const int bnn = (lane & 31) * 4;
  auto stage_B = [&](int nb, int k0) {
#pragma unroll
    for (int r = 0; r < 2; r++) {
      const int c = r * 2 + wv;
      const float* gp = g.B + (size_t)(k0 + c * 2 + bkk) * N + n0 + bnn;
      uint32_t m0v = (uint32_t)((2048 + nb * 1024 + c * 256) * 4);
      m0v = __builtin_amdgcn_readfirstlane(m0v);
      asm volatile("s_mov_b32 m0, %0\n\t"
                   "global_load_lds_dwordx4 %1, off\n\t"
                   :: "s"(m0v), "v"(gp) : "memory");
    }
  };

  // ---- A tile write: reg -> LDS transposed [k][m] (8 scalar ds_writes) ----
  auto write_A = [&](int nb) {
    const int abase = nb * 1024;
#pragma unroll
    for (int c = 0; c < 2; c++)
#pragma unroll
      for (int j = 0; j < 4; j++)
        smem[abase + (4 * c + j) * 128 + am] = av[c][j];
  };

  // ---- prologue: tile 0 into buf 0, prefetch A(tile 1) ----
  load_A(ks);
  stage_B(0, ks);
  write_A(0);
  load_A(ks + KB);                        // NT >= 2 always
  asm volatile("s_waitcnt vmcnt(0)" ::: "memory");
  __syncthreads();

  for (int it = 0; it < NT; ++it) {
    const int k0 = ks + it * KB;
    const int abase = (it & 1) * 1024;
    const int bbase = 2048 + (it & 1) * 1024;

    if (it + 1 < NT) {
      const int nb = (it + 1) & 1;
      stage_B(nb, k0 + KB);               // async -> other buffer
      write_A(nb);                        // ds_write, overlaps FMAs below
      if (it + 2 < NT) load_A(k0 + 2 * KB);
    }

    // ---- inner k (ascending, single accumulator per output) ----
#pragma unroll
    for (int k = 0; k < KB; k++) {
      f32x4 a0 = *(const f32x4*)&smem[abase + k * 128 + ty * 16];
      f32x4 a1 = *(const f32x4*)&smem[abase + k * 128 + ty * 16 + 4];
      f32x4 a2 = *(const f32x4*)&smem[abase + k * 128 + ty * 16 + 8];
      f32x4 a3 = *(const f32x4*)&smem[abase + k * 128 + ty * 16 + 12];
      f32x4 b0 = *(const f32x4*)&smem[bbase + k * 128 + tx * 4];
      f32x4 b1 = *(const f32x4*)&smem[bbase + k * 128 + 64 + tx * 4];
      float a[16] = {a0[0], a0[1], a0[2], a0[3], a1[0], a1[1], a1[2], a1[3],
                     a2[0], a2[1], a2[2], a2[3], a3[0], a3[1], a3[2], a3[3]};
      float b[8]  = {b0[0], b0[1], b0[2], b0[3], b1[0], b1[1], b1[2], b1[3]};
#pragma unroll
      for (int i = 0; i < 16; i++)
#pragma unroll
        for (int j = 0; j < 8; j++)
          acc[i][j] = __fmaf_rn(a[i], b[j], acc[i][j]);
    }

    asm volatile("s_waitcnt vmcnt(0)" ::: "memory");   // next tile's B landed
    __syncthreads();                                   // writes visible, reads done
  }

  // ---- store chunk partial sums ----
#pragma unroll
  for (int i = 0; i < 16; i++) {
    float* cp = C + (size_t)(m0 + ty * 16 + i) * N + n0;
    f32x4 v0 = {acc[i][0], acc[i][1], acc[i][2], acc[i][3]};
    f32x4 v1 = {acc[i][4], acc[i][5], acc[i][6], acc[i][7]};
    *(f32x4*)(cp + tx * 4) = v0;
    *(f32x4*)(cp + 64 + tx * 4) = v1;
  }
}

// ============================================================================
// p/t filters: in-order 9-chunk reduction (bitwise = sequential RMW adds),
// then exact np LIF chains. P/Tf are post-update states.
// ============================================================================
__global__ __launch_bounds__(256) void filter_pt9(const float* __restrict__ Cp,
                                                  const float* __restrict__ Ct,
                                                  float* __restrict__ P,
                                                  float* __restrict__ Tf) {
  const size_t CH = (size_t)T_WIN * BSZ * FDIM;   // 262144 floats
  int idx = blockIdx.x * 256 + threadIdx.x;   // 16384: (b, f/4)
  int b = idx >> 7;
  int fc = (idx & 127) << 2;
  f32x4 p = {0.f, 0.f, 0.f, 0.f}, t = {0.f, 0.f, 0.f, 0.f};
  for (int tt = 0; tt < T_WIN; tt++) {
    size_t o = (size_t)(tt * BSZ + b) * FDIM + fc;
    f32x4 x = *(const f32x4*)&Cp[o];
    f32x4 y = *(const f32x4*)&Ct[o];
    for (int q = 1; q < 9; q++) {
      f32x4 xq = *(const f32x4*)&Cp[o + q * CH];
      f32x4 yq = *(const f32x4*)&Ct[o + q * CH];
#pragma unroll
      for (int c = 0; c < 4; c++) { x[c] = __fadd_rn(x[c], xq[c]); y[c] = __fadd_rn(y[c], yq[c]); }
    }
#pragma unroll
    for (int c = 0; c < 4; c++) {
      p[c] = __fadd_rn(p[c], __fmul_rn(__fsub_rn(x[c], p[c]), 0.5f));
      t[c] = __fadd_rn(t[c], __fmul_rn(__fsub_rn(y[c], t[c]), 0.5f));
    }
    *(f32x4*)&P[o] = p;
    *(f32x4*)&Tf[o] = t;
  }
}

// ============================================================================
// soma LIF: in-order 9-chunk reduction of dist, then exact np chain -> spikes.
// ============================================================================
__global__ __launch_bounds__(256) void lif_soma9(const float* __restrict__ Cd,
                                                 const float* __restrict__ P,
                                                 const float* __restrict__ Tf,
                                                 uint8_t* __restrict__ emb) {
  const size_t CH = (size_t)T_WIN * ROWS * FDIM;  // 16,777,216 floats
  int idx = blockIdx.x * 256 + threadIdx.x;   // 1,048,576: (r, f/4)
  int r = idx >> 7;
  int fc = (idx & 127) << 2;
  int b = r >> 6;
  f32x4 d = {0.f, 0.f, 0.f, 0.f}, soma = {0.f, 0.f, 0.f, 0.f};
#pragma unroll
  for (int t = 0; t < T_WIN; t++) {
    size_t o = (size_t)(t * ROWS + r) * FDIM + fc;
    f32x4 x = *(const f32x4*)&Cd[o];
#pragma unroll
    for (int q = 1; q < 9; q++) {
      f32x4 xq = *(const f32x4*)&Cd[o + q * CH];
#pragma unroll
      for (int c = 0; c < 4; c++) x[c] = __fadd_rn(x[c], xq[c]);
    }
    f32x4 pv = *(const f32x4*)&P[(size_t)(t * BSZ + b) * FDIM + fc];
    f32x4 tv = *(const f32x4*)&Tf[(size_t)(t * BSZ + b) * FDIM + fc];
    uint32_t bits = 0;
#pragma unroll
    for (int c = 0; c < 4; c++) {
      d[c] = __fadd_rn(d[c], __fmul_rn(__fsub_rn(x[c], d[c]), 0.5f));
      float pd = __fmul_rn(pv[c], d[c]);          // p*d (must NOT contract)
      float u  = __fadd_rn(pd, tv[c]);            // + t
      float w  = __fsub_rn(u, soma[c]);           // - soma
      soma[c] = __fadd_rn(soma[c], __fmul_rn(w, 0.5f));
      if (soma[c] >= 0.5f) { bits |= (1u << (8 * c)); soma[c] = 0.f; }
    }
    *(uint32_t*)&emb[o] = bits;
  }
}

// ============================================================================
// hidden LIF: in-order 2-chunk reduction of H, +b1 first, exact chain -> counts.
// ============================================================================
__global__ __launch_bounds__(256) void lif_hidden2(const float* __restrict__ Hc,
                                                   const float* __restrict__ b1,
                                                   uint8_t* __restrict__ cnt) {
  const size_t CH = (size_t)T_WIN * ROWS * FDIM;
  int idx = blockIdx.x * 256 + threadIdx.x;   // (r, f/4)
  int r = idx >> 7;
  int fc = (idx & 127) << 2;
  f32x4 bb = *(const f32x4*)&b1[fc];
  f32x4 lif = {0.f, 0.f, 0.f, 0.f};
  uint32_t counts = 0;
#pragma unroll
  for (int t = 0; t < T_WIN; t++) {
    size_t o = (size_t)(t * ROWS + r) * FDIM + fc;
    f32x4 h0 = *(const f32x4*)&Hc[o];
    f32x4 h1 = *(const f32x4*)&Hc[o + CH];
#pragma unroll
    for (int c = 0; c < 4; c++) {
      float hv = __fadd_rn(__fadd_rn(h0[c], h1[c]), bb[c]);
      lif[c] = __fadd_rn(lif[c], __fmul_rn(__fsub_rn(hv, lif[c]), 0.5f));
      if (lif[c] >= 0.5f) { counts += (1u << (8 * c)); lif[c] = 0.f; }
    }
  }
  *(uint32_t*)&cnt[(size_t)r * FDIM + fc] = counts;
}

// ============================================================================
// out[b,l,s] = sum_k (cnt[r,k]/4)*W2[k,l] + b2[l]; k ascending, zero-skip
// bitwise exact (counts/4 are exact). Writes final output directly.
// ============================================================================
__global__ __launch_bounds__(256) void out_kernel(const uint8_t* __restrict__ cnt,
                                                  const float* __restrict__ W2,
                                                  const float* __restrict__ b2,
                                                  float* __restrict__ out) {
  int idx = blockIdx.x * 256 + threadIdx.x;   // 147456 = 8192*18
  int r = idx / LDIM;
  int j = idx - r * LDIM;
  const uint4* crow = (const uint4*)(cnt + (size_t)r * HDIM);
  float acc = 0.f;
  for (int q = 0; q < HDIM / 16; q++) {
    uint4 wrd = crow[q];
    uint32_t u[4] = {wrd.x, wrd.y, wrd.z, wrd.w};
#pragma unroll
    for (int wq = 0; wq < 4; wq++)
#pragma unroll
      for (int s = 0; s < 4; s++) {
        uint32_t c = (u[wq] >> (8 * s)) & 255u;
        if (c) acc = __fmaf_rn((float)c * 0.25f, W2[(16 * q + 4 * wq + s) * LDIM + j], acc);
      }
  }
  int b = r >> 6, s = r & 63;
  out[(size_t)b * (LDIM * SSZ) + j * SSZ + s] = __fadd_rn(acc, b2[j]);
}

// ---------- workspace layout (~616 MB; harness ws is ~1.6 GB per fill size) ----------
// Cd   9 x 64 MB  @ 0            (603,979,776)   dist chunk partial sums
//   (Hc 2 x 64 MB aliases Cd[0..1] — Cd dead once lif_soma9 completes)
// Cp   9 x 1 MB   @ 603,979,776  (  9,437,184)
// Ct   9 x 1 MB   @ 613,416,960  (  9,437,184)
// P    1 MB       @ 622,854,144
// Tf   1 MB       @ 623,902,720
// emb  16 MB      @ 624,951,296
// cnt  4 MB       @ 641,728,512   -> total 645,922,816

extern "C" void kernel_launch(void* const* d_in, const int* in_sizes, int n_in,
                              void* d_out, int out_size, void* d_ws, size_t ws_size,
                              hipStream_t stream) {
  const float* se     = (const float*)d_in[0];
  const float* te     = (const float*)d_in[1];
  const float* ee     = (const float*)d_in[2];
  const float* Wprox  = (const float*)d_in[3];
  const float* Wdist  = (const float*)d_in[4];
  const float* Wtrunk = (const float*)d_in[5];
  const float* W1     = (const float*)d_in[6];
  const float* b1     = (const float*)d_in[7];
  const float* W2     = (const float*)d_in[8];
  const float* b2     = (const float*)d_in[9];

  char* ws = (char*)d_ws;
  float*   Cd   = (float*)(ws);
  float*   Hc   = (float*)(ws);                 // aliases Cd[0..1] (dead by then)
  float*   Cp   = (float*)(ws + 603979776);
  float*   Ct   = (float*)(ws + 613416960);
  float*   P    = (float*)(ws + 622854144);
  float*   Tf   = (float*)(ws + 623902720);
  uint8_t* emb8 = (uint8_t*)(ws + 624951296);
  uint8_t* cnt8 = (uint8_t*)(ws + 641728512);

  // 1. ALL input-GEMM K-chunks in one launch (z = chunk 0..8).
  GArgs gd{te, Wdist, Cd, T_WIN * ROWS};
  GArgs gp{se, Wprox, Cp, T_WIN * BSZ};
  GArgs gt{ee, Wtrunk, Ct, T_WIN * BSZ};
  gemm_chunks<0, 1><<<dim3(1056, 1, 9), 128, 0, stream>>>(gd, gp, gt, FDIM, DDIM, 0);

  // 2. p/t filters (9-chunk in-order reduce + exact chains)
  filter_pt9<<<64, 256, 0, stream>>>(Cp, Ct, P, Tf);

  // 3. soma LIF (9-chunk in-order reduce + exact chains) -> binary spikes
  lif_soma9<<<4096, 256, 0, stream>>>(Cd, P, Tf, emb8);

  // 4. H = emb @ W1, both K-chunks {0..256,256..512} in one launch (over Cd, dead)
  GArgs gh{emb8, W1, Hc, T_WIN * ROWS};
  gemm_chunks<1, 0><<<dim3(1024, 1, 2), 128, 0, stream>>>(gh, gh, gh, HDIM, FDIM, 1);

  // 5. hidden LIF (2-chunk in-order reduce) -> spike counts
  lif_hidden2<<<4096, 256, 0, stream>>>(Hc, b1, cnt8);

  // 6. output GEMM + b2 + [B,LAST,S] transpose, fp32
  out_kernel<<<576, 256, 0, stream>>>(cnt8, W2, b2, (float*)d_out);
}

// Round 5
// 1997.932 us; speedup vs baseline: 1.2161x; 1.0083x over previous
//
#include <hip/hip_runtime.h>
#include <stdint.h>

typedef __attribute__((ext_vector_type(4))) float f32x4;

#define T_WIN 4
#define BSZ   128
#define SSZ   64
#define DDIM  3136
#define FDIM  512
#define HDIM  512
#define LDIM  18
#define ROWS  8192   // B*S
#define KB    16

// Per-gemm chunk-buffer stride = M*N floats; chunk q lives at C + q*M*N.
struct GArgs { const void* A; const float* B; float* C; int M; };

// OpenBLAS K-chunk bounds for K=3136 (GEMM_Q=384, tail halving) — validated R3/R4.
__device__ __forceinline__ void kchunk3136(int z, int& ks, int& ke) {
  ks = (z <= 7) ? 384 * z : 2912;
  ke = (z <= 6) ? 384 * (z + 1) : ((z == 7) ? 2912 : 3136);
}

// ============================================================================
// fp32 GEMM, all K-chunks in ONE launch (z = chunk): writes chunk partial sum
// (ascending-k single-accumulator fma chain from zero) to its own buffer.
// The in-order chunk adds happen in the consumer kernels (bitwise = RMW chain).
//
// R9 = R7's 256-thread / 8x8-acc / KB=16 structure with __launch_bounds__(256,3).
// Round history (counter evidence):
//  - 128 thr, 16x8 acc (R1/R2/R4): occupancy PINNED at 21.5% at any LDS size —
//    unified reg file (128 AGPR acc + ~128 VGPR ~= 256/wave) = 2 waves/SIMD cap.
//  - 256 thr, (256,4) [R3]: 128-reg budget vs ~154 need -> hot-loop scratch
//    spill (WRITE_SIZE 608MB -> 2.06GB), 33 TF. NEVER squeeze below need.
//  - (256,3): 170-reg budget > ~154 need -> no spill, 3 waves/SIMD.
// Per-output FMA chain (ascending k, single acc) UNCHANGED -> bitwise identical.
//
// smem layout (floats): A0 [0,2048) A1 [2048,4096) B0 [4096,6144) B1 [6144,8192)
// LDS byte offsets for M0: B0=16384, B1=24576.
//
// SMALLS: logical ids >= 1024 handle the prox/trunk 512-row GEMMs (g1/g2).
// AMODE 0: A fp32;  AMODE 1: A uint8 (0/1 spikes -> exact products).
// ============================================================================
template<int AMODE, int SMALLS>
__global__ __launch_bounds__(256, 3) void gemm_chunks(GArgs g0, GArgs g1, GArgs g2,
                                                      int N, int K, int kcmode) {
  // bijective XCD swizzle (nwg % 8 == 0): keeps the 4 y-siblings of each xb
  // (same A K-slice) co-resident on one XCD -> A L2-hit 3x. (validated R5)
  const int chunk = gridDim.x >> 3;
  const int orig  = blockIdx.x;
  const int lin   = (orig & 7) * chunk + (orig >> 3);

  GArgs g = g0;
  int xb, y;
  if (SMALLS && lin >= 1024) {
    const int sidx = lin - 1024;          // 0..31
    g  = (sidx >> 4) ? g2 : g1;
    xb = (sidx >> 2) & 3;
    y  = sidx & 3;
  } else {
    xb = lin >> 2;
    y  = lin & 3;
  }

  int ks, ke;
  if (kcmode == 0) kchunk3136(blockIdx.z, ks, ke);
  else { ks = blockIdx.z * 256; ke = ks + 256; }
  const int NT = (ke - ks) / KB;          // 24 / 14 / 16 — always >= 2

  const int m0 = xb * 128;
  const int n0 = y * 128;
  float* C = g.C + (size_t)blockIdx.z * g.M * N;

  __shared__ float smem[8192];            // 32 KB: A dbuf + B dbuf

  const int tid = threadIdx.x;
  const int tx = tid & 15;            // n: cols tx*4..+3 and 64+tx*4..+3
  const int ty = tid >> 4;            // m: rows ty*8..+7  (16 groups x 8 = 128)
  const int arow = tid >> 1;          // A stage: half-row per thread
  const int ahalf = tid & 1;          // 8 k-floats each
  const int lane = tid & 63;
  const int wv   = tid >> 6;          // wave 0..3

  const float*   Af = (const float*)g.A;
  const uint8_t* A8 = (const uint8_t*)g.A;

  float acc[8][8];
#pragma unroll
  for (int i = 0; i < 8; i++)
#pragma unroll
    for (int j = 0; j < 8; j++) acc[i][j] = 0.f;

  // ---- A prefetch registers (transpose path): 8 k-floats of one half-row ----
  f32x4 av[2];
  auto load_A = [&](int k0) {
    if (AMODE == 0) {
      const float* ap = Af + (size_t)(m0 + arow) * K + k0 + ahalf * 8;
#pragma unroll
      for (int c = 0; c < 2; c++) av[c] = *(const f32x4*)(ap + 4 * c);
    } else {
      uint2 wrd = *(const uint2*)(A8 + (size_t)(m0 + arow) * K + k0 + ahalf * 8);
      uint32_t u[2] = {wrd.x, wrd.y};
#pragma unroll
      for (int c = 0; c < 2; c++) {
        av[c][0] = (float)(u[c] & 255u);
        av[c][1] = (float)((u[c] >> 8) & 255u);
        av[c][2] = (float)((u[c] >> 16) & 255u);
        av[c][3] = (float)((u[c] >> 24) & 255u);
      }
    }
  };

  // ---- B tile stage: global_load_lds, 1 KB per wave-instr, 8 chunks/tile ----
  // chunk c covers floats [c*256, c*256+256) of the [16][128] tile:
  // lane covers k = c*2 + (lane>>5), n = (lane&31)*4.  4 waves x 2 instrs.
  const int bkk = lane >> 5;
  const int bnn = (lane & 31) * 4;
  auto stage_B = [&](int nb, int k0) {
#pragma unroll
    for (int r = 0; r < 2; r++) {
      const int c = r * 4 + wv;
      const float* gp = g.B + (size_t)(k0 + c * 2 + bkk) * N + n0 + bnn;
      uint32_t m0v = (uint32_t)((4096 + nb * 2048 + c * 256) * 4);
      m0v = __builtin_amdgcn_readfirstlane(m0v);
      asm volatile("s_mov_b32 m0, %0\n\t"
                   "global_load_lds_dwordx4 %1, off\n\t"
                   :: "s"(m0v), "v"(gp) : "memory");
    }
  };

  // ---- A tile write: reg -> LDS transposed [k][m] (8 scalar ds_writes) ----
  auto write_A = [&](int nb) {
    const int abase = nb * 2048;
#pragma unroll
    for (int c = 0; c < 2; c++)
#pragma unroll
      for (int j = 0; j < 4; j++)
        smem[abase + (ahalf * 8 + 4 * c + j) * 128 + arow] = av[c][j];
  };

  // ---- prologue: tile 0 into buf 0, prefetch A(tile 1) ----
  load_A(ks);
  stage_B(0, ks);
  write_A(0);
  load_A(ks + KB);                        // NT >= 2 always
  asm volatile("s_waitcnt vmcnt(0)" ::: "memory");
  __syncthreads();

  for (int it = 0; it < NT; ++it) {
    const int k0 = ks + it * KB;
    const int abase = (it & 1) * 2048;
    const int bbase = 4096 + (it & 1) * 2048;

    if (it + 1 < NT) {
      const int nb = (it + 1) & 1;
      stage_B(nb, k0 + KB);               // async -> other buffer
      write_A(nb);                        // ds_write, overlaps FMAs below
      if (it + 2 < NT) load_A(k0 + 2 * KB);
    }

    // ---- inner k (ascending, single accumulator per output) ----
#pragma unroll 4
    for (int k = 0; k < KB; k++) {
      f32x4 a0 = *(const f32x4*)&smem[abase + k * 128 + ty * 8];
      f32x4 a1 = *(const f32x4*)&smem[abase + k * 128 + ty * 8 + 4];
      f32x4 b0 = *(const f32x4*)&smem[bbase + k * 128 + tx * 4];
      f32x4 b1 = *(const f32x4*)&smem[bbase + k * 128 + 64 + tx * 4];
      float a[8] = {a0[0], a0[1], a0[2], a0[3], a1[0], a1[1], a1[2], a1[3]};
      float b[8] = {b0[0], b0[1], b0[2], b0[3], b1[0], b1[1], b1[2], b1[3]};
#pragma unroll
      for (int i = 0; i < 8; i++)
#pragma unroll
        for (int j = 0; j < 8; j++)
          acc[i][j] = __fmaf_rn(a[i], b[j], acc[i][j]);
    }

    asm volatile("s_waitcnt vmcnt(0)" ::: "memory");   // next tile's B landed
    __syncthreads();                                   // writes visible, reads done
  }

  // ---- store chunk partial sums ----
#pragma unroll
  for (int i = 0; i < 8; i++) {
    float* cp = C + (size_t)(m0 + ty * 8 + i) * N + n0;
    f32x4 v0 = {acc[i][0], acc[i][1], acc[i][2], acc[i][3]};
    f32x4 v1 = {acc[i][4], acc[i][5], acc[i][6], acc[i][7]};
    *(f32x4*)(cp + tx * 4) = v0;
    *(f32x4*)(cp + 64 + tx * 4) = v1;
  }
}

// ============================================================================
// p/t filters: in-order 9-chunk reduction (bitwise = sequential RMW adds),
// then exact np LIF chains. P/Tf are post-update states.
// ============================================================================
__global__ __launch_bounds__(256) void filter_pt9(const float* __restrict__ Cp,
                                                  const float* __restrict__ Ct,
                                                  float* __restrict__ P,
                                                  float* __restrict__ Tf) {
  const size_t CH = (size_t)T_WIN * BSZ * FDIM;   // 262144 floats
  int idx = blockIdx.x * 256 + threadIdx.x;   // 16384: (b, f/4)
  int b = idx >> 7;
  int fc = (idx & 127) << 2;
  f32x4 p = {0.f, 0.f, 0.f, 0.f}, t = {0.f, 0.f, 0.f, 0.f};
  for (int tt = 0; tt < T_WIN; tt++) {
    size_t o = (size_t)(tt * BSZ + b) * FDIM + fc;
    f32x4 x = *(const f32x4*)&Cp[o];
    f32x4 y = *(const f32x4*)&Ct[o];
    for (int q = 1; q < 9; q++) {
      f32x4 xq = *(const f32x4*)&Cp[o + q * CH];
      f32x4 yq = *(const f32x4*)&Ct[o + q * CH];
#pragma unroll
      for (int c = 0; c < 4; c++) { x[c] = __fadd_rn(x[c], xq[c]); y[c] = __fadd_rn(y[c], yq[c]); }
    }
#pragma unroll
    for (int c = 0; c < 4; c++) {
      p[c] = __fadd_rn(p[c], __fmul_rn(__fsub_rn(x[c], p[c]), 0.5f));
      t[c] = __fadd_rn(t[c], __fmul_rn(__fsub_rn(y[c], t[c]), 0.5f));
    }
    *(f32x4*)&P[o] = p;
    *(f32x4*)&Tf[o] = t;
  }
}

// ============================================================================
// soma LIF: in-order 9-chunk reduction of dist, then exact np chain -> spikes.
// ============================================================================
__global__ __launch_bounds__(256) void lif_soma9(const float* __restrict__ Cd,
                                                 const float* __restrict__ P,
                                                 const float* __restrict__ Tf,
                                                 uint8_t* __restrict__ emb) {
  const size_t CH = (size_t)T_WIN * ROWS * FDIM;  // 16,777,216 floats
  int idx = blockIdx.x * 256 + threadIdx.x;   // 1,048,576: (r, f/4)
  int r = idx >> 7;
  int fc = (idx & 127) << 2;
  int b = r >> 6;
  f32x4 d = {0.f, 0.f, 0.f, 0.f}, soma = {0.f, 0.f, 0.f, 0.f};
#pragma unroll
  for (int t = 0; t < T_WIN; t++) {
    size_t o = (size_t)(t * ROWS + r) * FDIM + fc;
    f32x4 x = *(const f32x4*)&Cd[o];
#pragma unroll
    for (int q = 1; q < 9; q++) {
      f32x4 xq = *(const f32x4*)&Cd[o + q * CH];
#pragma unroll
      for (int c = 0; c < 4; c++) x[c] = __fadd_rn(x[c], xq[c]);
    }
    f32x4 pv = *(const f32x4*)&P[(size_t)(t * BSZ + b) * FDIM + fc];
    f32x4 tv = *(const f32x4*)&Tf[(size_t)(t * BSZ + b) * FDIM + fc];
    uint32_t bits = 0;
#pragma unroll
    for (int c = 0; c < 4; c++) {
      d[c] = __fadd_rn(d[c], __fmul_rn(__fsub_rn(x[c], d[c]), 0.5f));
      float pd = __fmul_rn(pv[c], d[c]);          // p*d (must NOT contract)
      float u  = __fadd_rn(pd, tv[c]);            // + t
      float w  = __fsub_rn(u, soma[c]);           // - soma
      soma[c] = __fadd_rn(soma[c], __fmul_rn(w, 0.5f));
      if (soma[c] >= 0.5f) { bits |= (1u << (8 * c)); soma[c] = 0.f; }
    }
    *(uint32_t*)&emb[o] = bits;
  }
}

// ============================================================================
// hidden LIF: in-order 2-chunk reduction of H, +b1 first, exact chain -> counts.
// ============================================================================
__global__ __launch_bounds__(256) void lif_hidden2(const float* __restrict__ Hc,
                                                   const float* __restrict__ b1,
                                                   uint8_t* __restrict__ cnt) {
  const size_t CH = (size_t)T_WIN * ROWS * FDIM;
  int idx = blockIdx.x * 256 + threadIdx.x;   // (r, f/4)
  int r = idx >> 7;
  int fc = (idx & 127) << 2;
  f32x4 bb = *(const f32x4*)&b1[fc];
  f32x4 lif = {0.f, 0.f, 0.f, 0.f};
  uint32_t counts = 0;
#pragma unroll
  for (int t = 0; t < T_WIN; t++) {
    size_t o = (size_t)(t * ROWS + r) * FDIM + fc;
    f32x4 h0 = *(const f32x4*)&Hc[o];
    f32x4 h1 = *(const f32x4*)&Hc[o + CH];
#pragma unroll
    for (int c = 0; c < 4; c++) {
      float hv = __fadd_rn(__fadd_rn(h0[c], h1[c]), bb[c]);
      lif[c] = __fadd_rn(lif[c], __fmul_rn(__fsub_rn(hv, lif[c]), 0.5f));
      if (lif[c] >= 0.5f) { counts += (1u << (8 * c)); lif[c] = 0.f; }
    }
  }
  *(uint32_t*)&cnt[(size_t)r * FDIM + fc] = counts;
}

// ============================================================================
// out[b,l,s] = sum_k (cnt[r,k]/4)*W2[k,l] + b2[l]; k ascending, zero-skip
// bitwise exact (counts/4 are exact). Writes final output directly.
// ============================================================================
__global__ __launch_bounds__(256) void out_kernel(const uint8_t* __restrict__ cnt,
                                                  const float* __restrict__ W2,
                                                  const float* __restrict__ b2,
                                                  float* __restrict__ out) {
  int idx = blockIdx.x * 256 + threadIdx.x;   // 147456 = 8192*18
  int r = idx / LDIM;
  int j = idx - r * LDIM;
  const uint4* crow = (const uint4*)(cnt + (size_t)r * HDIM);
  float acc = 0.f;
  for (int q = 0; q < HDIM / 16; q++) {
    uint4 wrd = crow[q];
    uint32_t u[4] = {wrd.x, wrd.y, wrd.z, wrd.w};
#pragma unroll
    for (int wq = 0; wq < 4; wq++)
#pragma unroll
      for (int s = 0; s < 4; s++) {
        uint32_t c = (u[wq] >> (8 * s)) & 255u;
        if (c) acc = __fmaf_rn((float)c * 0.25f, W2[(16 * q + 4 * wq + s) * LDIM + j], acc);
      }
  }
  int b = r >> 6, s = r & 63;
  out[(size_t)b * (LDIM * SSZ) + j * SSZ + s] = __fadd_rn(acc, b2[j]);
}

// ---------- workspace layout (~616 MB; harness ws is ~1.6 GB per fill size) ----------
// Cd   9 x 64 MB  @ 0            (603,979,776)   dist chunk partial sums
//   (Hc 2 x 64 MB aliases Cd[0..1] — Cd dead once lif_soma9 completes)
// Cp   9 x 1 MB   @ 603,979,776  (  9,437,184)
// Ct   9 x 1 MB   @ 613,416,960  (  9,437,184)
// P    1 MB       @ 622,854,144
// Tf   1 MB       @ 623,902,720
// emb  16 MB      @ 624,951,296
// cnt  4 MB       @ 641,728,512   -> total 645,922,816

extern "C" void kernel_launch(void* const* d_in, const int* in_sizes, int n_in,
                              void* d_out, int out_size, void* d_ws, size_t ws_size,
                              hipStream_t stream) {
  const float* se     = (const float*)d_in[0];
  const float* te     = (const float*)d_in[1];
  const float* ee     = (const float*)d_in[2];
  const float* Wprox  = (const float*)d_in[3];
  const float* Wdist  = (const float*)d_in[4];
  const float* Wtrunk = (const float*)d_in[5];
  const float* W1     = (const float*)d_in[6];
  const float* b1     = (const float*)d_in[7];
  const float* W2     = (const float*)d_in[8];
  const float* b2     = (const float*)d_in[9];

  char* ws = (char*)d_ws;
  float*   Cd   = (float*)(ws);
  float*   Hc   = (float*)(ws);                 // aliases Cd[0..1] (dead by then)
  float*   Cp   = (float*)(ws + 603979776);
  float*   Ct   = (float*)(ws + 613416960);
  float*   P    = (float*)(ws + 622854144);
  float*   Tf   = (float*)(ws + 623902720);
  uint8_t* emb8 = (uint8_t*)(ws + 624951296);
  uint8_t* cnt8 = (uint8_t*)(ws + 641728512);

  // 1. ALL input-GEMM K-chunks in one launch (z = chunk 0..8).
  GArgs gd{te, Wdist, Cd, T_WIN * ROWS};
  GArgs gp{se, Wprox, Cp, T_WIN * BSZ};
  GArgs gt{ee, Wtrunk, Ct, T_WIN * BSZ};
  gemm_chunks<0, 1><<<dim3(1056, 1, 9), 256, 0, stream>>>(gd, gp, gt, FDIM, DDIM, 0);

  // 2. p/t filters (9-chunk in-order reduce + exact chains)
  filter_pt9<<<64, 256, 0, stream>>>(Cp, Ct, P, Tf);

  // 3. soma LIF (9-chunk in-order reduce + exact chains) -> binary spikes
  lif_soma9<<<4096, 256, 0, stream>>>(Cd, P, Tf, emb8);

  // 4. H = emb @ W1, both K-chunks {0..256,256..512} in one launch (over Cd, dead)
  GArgs gh{emb8, W1, Hc, T_WIN * ROWS};
  gemm_chunks<1, 0><<<dim3(1024, 1, 2), 256, 0, stream>>>(gh, gh, gh, HDIM, FDIM, 1);

  // 5. hidden LIF (2-chunk in-order reduce) -> spike counts
  lif_hidden2<<<4096, 256, 0, stream>>>(Hc, b1, cnt8);

  // 6. output GEMM + b2 + [B,LAST,S] transpose, fp32
  out_kernel<<<576, 256, 0, stream>>>(cnt8, W2, b2, (float*)d_out);
}